// Round 2
// baseline (582.378 us; speedup 1.0000x reference)
//
#include <hip/hip_runtime.h>
#include <hip/hip_bf16.h>

namespace {

constexpr int kCin   = 128;
constexpr int kHW    = 12544;   // 112*112
constexpr int kW     = 112;
constexpr int kGrps  = 49;      // per image: 49 blocks * 4 tiles * 64 tokens = 12544
constexpr size_t kOut1Off = (size_t)16 * 128 * kHW;  // element offset of assignment map

__device__ __forceinline__ float bf2f(unsigned short u) {
  union { unsigned int i; float f; } v;
  v.i = ((unsigned int)u) << 16;
  return v.f;
}

__device__ __forceinline__ unsigned short f2bf(float f) {
  union { float f; unsigned int i; } v;
  v.f = f;
  unsigned int x = v.i;
  x += 0x7fffu + ((x >> 16) & 1u);   // RNE
  return (unsigned short)(x >> 16);
}

// ---- dtype-templated load/store helpers (BF=true: bf16, else fp32) ----
template <bool BF>
__device__ __forceinline__ float ld1(const void* p, size_t i) {
  if constexpr (BF) return bf2f(((const unsigned short*)p)[i]);
  else              return ((const float*)p)[i];
}
template <bool BF>
__device__ __forceinline__ void ld4(const void* p, size_t i, float o[4]) {
  if constexpr (BF) {
    const ushort4 u = *reinterpret_cast<const ushort4*>((const unsigned short*)p + i);
    o[0] = bf2f(u.x); o[1] = bf2f(u.y); o[2] = bf2f(u.z); o[3] = bf2f(u.w);
  } else {
    const float4 u = *reinterpret_cast<const float4*>((const float*)p + i);
    o[0] = u.x; o[1] = u.y; o[2] = u.z; o[3] = u.w;
  }
}
template <bool BF>
__device__ __forceinline__ void st1(void* p, size_t i, float v) {
  if constexpr (BF) ((unsigned short*)p)[i] = f2bf(v);
  else              ((float*)p)[i] = v;
}
template <bool BF>
__device__ __forceinline__ void st4(void* p, size_t i, const float v[4]) {
  if constexpr (BF) {
    ushort4 u;
    u.x = f2bf(v[0]); u.y = f2bf(v[1]); u.z = f2bf(v[2]); u.w = f2bf(v[3]);
    *reinterpret_cast<ushort4*>((unsigned short*)p + i) = u;
  } else {
    float4 u;
    u.x = v[0]; u.y = v[1]; u.z = v[2]; u.w = v[3];
    *reinterpret_cast<float4*>((float*)p + i) = u;
  }
}

// ---------------------------------------------------------------------------
// Kernel 0: detect input dtype. bf16 f_w values are ~N(0, 0.09): none exceed 4.
// fp32 f_w read as bf16 pairs: ~25% of ushorts are mantissa garbage with
// uniform-random exponent -> |v|>4 for ~half of those. flag=1 means bf16.
// ---------------------------------------------------------------------------
__global__ void detect_dtype(const unsigned short* __restrict__ fw, int* __restrict__ flag) {
  __shared__ int cnt_s;
  if (threadIdx.x == 0) cnt_s = 0;
  __syncthreads();
  int c = 0;
  for (int i = threadIdx.x; i < 4096; i += 256) {
    const float v = bf2f(fw[i]);
    if (fabsf(v) > 4.0f) ++c;
  }
  atomicAdd(&cnt_s, c);
  __syncthreads();
  if (threadIdx.x == 0) flag[0] = (cnt_s > 100) ? 0 : 1;
}

// ---------------------------------------------------------------------------
// Kernel 1: per 64-token tile: f,v = convs (192x64 GEMM into LDS), per-token
// head-wise cosine sim vs centers + sigmoid + argmax, block-level reduction,
// atomics into global accumulators. (s, idx) staged into d_out channels 0..7.
// ---------------------------------------------------------------------------
struct SMain {
  float fv[192 * 65];           // rows 0..95 f, 96..191 v (pad 65)
  float cn[4][24];
  float s[4][64];
  unsigned char idx[4][64];
  unsigned char q[64];
};

template <bool BF>
__device__ __forceinline__ void main_body(
    SMain& sm,
    const void* __restrict__ x,  const void* __restrict__ f_w, const void* __restrict__ f_b,
    const void* __restrict__ v_w, const void* __restrict__ v_b,
    const void* __restrict__ sim_alpha, const void* __restrict__ sim_beta,
    const void* __restrict__ centers,
    void* __restrict__ out0,
    float* __restrict__ aggsum, float* __restrict__ vpool, float* __restrict__ cnt)
{
  const int tid = threadIdx.x;
  const int b   = blockIdx.x / kGrps;
  const int grp = blockIdx.x % kGrps;

  if (tid < 4) {
    float cv[24];
    float n2 = 0.f;
#pragma unroll
    for (int c = 0; c < 24; ++c) { cv[c] = ld1<BF>(centers, tid * 24 + c); n2 += cv[c] * cv[c]; }
    const float inv = 1.f / fmaxf(sqrtf(n2), 1e-12f);
#pragma unroll
    for (int c = 0; c < 24; ++c) sm.cn[tid][c] = cv[c] * inv;
  }
  const float alpha = ld1<BF>(sim_alpha, 0);
  const float beta  = ld1<BF>(sim_beta, 0);

  // GEMM mapping: 16x16 threads; rows ty*12..+11, cols tx*4..+3 (96=8*12, ty wave-uniform f/v)
  const int ty = tid >> 4;
  const int tx = tid & 15;
  const void*  wsel  = (ty < 8) ? f_w : v_w;
  const void*  bsel  = (ty < 8) ? f_b : v_b;
  const size_t wrow0 = (size_t)((ty < 8) ? ty * 12 : ty * 12 - 96);
  float bias[12];
#pragma unroll
  for (int r = 0; r < 12; ++r) bias[r] = ld1<BF>(bsel, wrow0 + r);

  const int e   = tid >> 6;
  const int tok = tid & 63;

  float agg_m[4]  = {0.f, 0.f, 0.f, 0.f};
  float pool_q[4] = {0.f, 0.f, 0.f, 0.f};
  float cacc = 0.f;
  const int ce = (tid - 96) >> 2;
  const int cm = (tid - 96) & 3;

  __syncthreads();

  for (int t = 0; t < 4; ++t) {
    const int hw0 = (grp * 4 + t) * 64;

    // ---- phase A: [f;v](192) x tokens(64) ----
    float acc[12][4];
#pragma unroll
    for (int r = 0; r < 12; ++r)
#pragma unroll
      for (int j = 0; j < 4; ++j) acc[r][j] = 0.f;

    const size_t xbase = ((size_t)b * kCin) * kHW + hw0 + tx * 4;
    for (int i = 0; i < 128; i += 4) {
      float xv[4][4];
#pragma unroll
      for (int ci = 0; ci < 4; ++ci) ld4<BF>(x, xbase + (size_t)(i + ci) * kHW, xv[ci]);
      float wv[12][4];
#pragma unroll
      for (int r = 0; r < 12; ++r) ld4<BF>(wsel, (wrow0 + r) * 128 + i, wv[r]);
#pragma unroll
      for (int r = 0; r < 12; ++r)
#pragma unroll
        for (int ci = 0; ci < 4; ++ci)
#pragma unroll
          for (int j = 0; j < 4; ++j)
            acc[r][j] = fmaf(wv[r][ci], xv[ci][j], acc[r][j]);
    }
#pragma unroll
    for (int r = 0; r < 12; ++r)
#pragma unroll
      for (int j = 0; j < 4; ++j)
        sm.fv[(ty * 12 + r) * 65 + tx * 4 + j] = acc[r][j] + bias[r];
    __syncthreads();

    // ---- phase B1: sim / sigmoid / argmax, stage (s, idx) into d_out ch 0..7 ----
    {
      float dm[4] = {0.f, 0.f, 0.f, 0.f};
      float n2 = 0.f;
#pragma unroll
      for (int c = 0; c < 24; ++c) {
        const float fc = sm.fv[(e * 24 + c) * 65 + tok];
        n2 += fc * fc;
        dm[0] += fc * sm.cn[0][c];
        dm[1] += fc * sm.cn[1][c];
        dm[2] += fc * sm.cn[2][c];
        dm[3] += fc * sm.cn[3][c];
      }
      const float inv = 1.f / fmaxf(sqrtf(n2), 1e-12f);
      float s[4];
#pragma unroll
      for (int m = 0; m < 4; ++m) {
        const float z = beta + alpha * dm[m] * inv;
        s[m] = 1.f / (1.f + __expf(-z));
      }
      float best = -1.f;
      int bi = 0;
#pragma unroll
      for (int m = 0; m < 4; ++m)
        if (s[m] > best) { best = s[m]; bi = m; }   // strict >: first max, like jnp.argmax

      const int hw = hw0 + tok;
      st1<BF>(out0, ((size_t)(b * 128 + e)) * kHW + hw, best);        // stage s
      st1<BF>(out0, ((size_t)(b * 128 + 4 + e)) * kHW + hw, (float)bi); // stage idx
      sm.s[e][tok]   = best;
      sm.idx[e][tok] = (unsigned char)bi;
      if (e == 0) {
        const int h = hw / kW;
        const int w = hw - h * kW;
        sm.q[tok] = (unsigned char)((h >= 56 ? 2 : 0) + (w >= 56 ? 1 : 0));
      }
    }
    __syncthreads();

    // ---- phase B2: block reduction over 64 tokens ----
    if (tid < 96) {
      const int row0 = (96 + tid) * 65;   // v row = channel tid
      const int eh = tid / 24;
      for (int t2 = 0; t2 < 64; ++t2) {
        const float v = sm.fv[row0 + t2];
        const float s = sm.s[eh][t2];
        const int  mi = sm.idx[eh][t2];
        const int  q  = sm.q[t2];
        const float sv = s * v;
        agg_m[0]  += (mi == 0) ? sv : 0.f;
        agg_m[1]  += (mi == 1) ? sv : 0.f;
        agg_m[2]  += (mi == 2) ? sv : 0.f;
        agg_m[3]  += (mi == 3) ? sv : 0.f;
        pool_q[0] += (q == 0) ? v : 0.f;
        pool_q[1] += (q == 1) ? v : 0.f;
        pool_q[2] += (q == 2) ? v : 0.f;
        pool_q[3] += (q == 3) ? v : 0.f;
      }
    } else if (tid < 112) {
      for (int t2 = 0; t2 < 64; ++t2) {
        const float s = sm.s[ce][t2];
        const int  mi = sm.idx[ce][t2];
        cacc += (mi == cm) ? s : 0.f;
      }
    }
    __syncthreads();
  }

  if (tid < 96) {
    const int eh = tid / 24;
    const int c  = tid % 24;
    const int bh = b * 4 + eh;
#pragma unroll
    for (int m = 0; m < 4; ++m) {
      atomicAdd(&aggsum[(bh * 4 + m) * 24 + c], agg_m[m]);
      atomicAdd(&vpool[(bh * 4 + m) * 24 + c], pool_q[m]);
    }
  } else if (tid < 112) {
    atomicAdd(&cnt[(b * 4 + ce) * 4 + cm], cacc);
  }
}

__global__ __launch_bounds__(256) void cluster_main(
    const int* __restrict__ flag,
    const void* x, const void* f_w, const void* f_b, const void* v_w, const void* v_b,
    const void* sim_alpha, const void* sim_beta, const void* centers,
    void* out0, float* aggsum, float* vpool, float* cnt)
{
  __shared__ SMain sm;
  if (*flag)
    main_body<true>(sm, x, f_w, f_b, v_w, v_b, sim_alpha, sim_beta, centers, out0, aggsum, vpool, cnt);
  else
    main_body<false>(sm, x, f_w, f_b, v_w, v_b, sim_alpha, sim_beta, centers, out0, aggsum, vpool, cnt);
}

// ---------------------------------------------------------------------------
// Kernel 2: aggf[bh][m][c] = (aggsum + vpool/3136) / (cnt + 1)
// ---------------------------------------------------------------------------
__global__ void cluster_finalize(const float* __restrict__ aggsum,
                                 const float* __restrict__ vpool,
                                 const float* __restrict__ cnt,
                                 float* __restrict__ aggf) {
  const int g = blockIdx.x * 256 + threadIdx.x;
  if (g < 64 * 4 * 24) {
    const int bhm = g / 24;
    aggf[g] = (aggsum[g] + vpool[g] * (1.f / 3136.f)) / (cnt[bhm] + 1.f);
  }
}

// ---------------------------------------------------------------------------
// Kernel 3: assignment map = staged idx of (b=0, head 0) — runs BEFORE proj
// overwrites the staging area. Raw element copy (idx 0..3 exact in both dtypes).
// ---------------------------------------------------------------------------
__global__ void cluster_amap(const int* __restrict__ flag, void* __restrict__ dout) {
  const int i = blockIdx.x * 256 + threadIdx.x;
  if (i >= kHW) return;
  const size_t src = (size_t)4 * kHW + i;   // b=0, channel 4 = staged idx head 0
  if (*flag) {
    unsigned short* o = (unsigned short*)dout;
    o[kOut1Off + i] = o[src];
  } else {
    float* o = (float*)dout;
    o[kOut1Off + i] = o[src];
  }
}

// ---------------------------------------------------------------------------
// Kernel 4: g[token] = s* · aggf[idx]; out = proj_w @ g + proj_b
// ---------------------------------------------------------------------------
struct SProj {
  float g[96 * 65];
  float af[384];
  float pb[128];
};

template <bool BF>
__device__ __forceinline__ void proj_body(
    SProj& sp,
    const void* __restrict__ proj_w, const void* __restrict__ proj_b,
    const float* __restrict__ aggf, void* __restrict__ out0)
{
  const int tid = threadIdx.x;
  const int b   = blockIdx.x / kGrps;
  const int grp = blockIdx.x % kGrps;

  for (int k = tid; k < 384; k += 256) sp.af[k] = aggf[b * 384 + k];
  if (tid < 128) sp.pb[tid] = ld1<BF>(proj_b, tid);

  const int e   = tid >> 6;
  const int tok = tid & 63;
  const int ty  = tid >> 4;
  const int tx  = tid & 15;
  __syncthreads();

  for (int t = 0; t < 4; ++t) {
    const int hw0 = (grp * 4 + t) * 64;
    const int hw  = hw0 + tok;
    const float sg = ld1<BF>(out0, ((size_t)(b * 128 + e)) * kHW + hw);
    const float iv = ld1<BF>(out0, ((size_t)(b * 128 + 4 + e)) * kHW + hw);
    const int   mi = (int)(iv + 0.5f);
    const float* af = &sp.af[(e * 4 + mi) * 24];
#pragma unroll
    for (int c = 0; c < 24; ++c)
      sp.g[(e * 24 + c) * 65 + tok] = sg * af[c];
    __syncthreads();

    float acc[8][4];
#pragma unroll
    for (int r = 0; r < 8; ++r)
#pragma unroll
      for (int j = 0; j < 4; ++j) acc[r][j] = 0.f;

    for (int k = 0; k < 96; k += 4) {
      float wv[8][4];
#pragma unroll
      for (int r = 0; r < 8; ++r) ld4<BF>(proj_w, (size_t)(ty * 8 + r) * 96 + k, wv[r]);
      float gv[4][4];
#pragma unroll
      for (int kk = 0; kk < 4; ++kk)
#pragma unroll
        for (int j = 0; j < 4; ++j)
          gv[kk][j] = sp.g[(k + kk) * 65 + tx * 4 + j];
#pragma unroll
      for (int r = 0; r < 8; ++r)
#pragma unroll
        for (int kk = 0; kk < 4; ++kk)
#pragma unroll
          for (int j = 0; j < 4; ++j)
            acc[r][j] = fmaf(wv[r][kk], gv[kk][j], acc[r][j]);
    }

    const size_t obase = ((size_t)b * 128) * kHW + hw0 + tx * 4;
#pragma unroll
    for (int r = 0; r < 8; ++r) {
      const int o = ty * 8 + r;
      float v[4];
#pragma unroll
      for (int j = 0; j < 4; ++j) v[j] = acc[r][j] + sp.pb[o];
      st4<BF>(out0, obase + (size_t)o * kHW, v);
    }
    __syncthreads();
  }
}

__global__ __launch_bounds__(256) void cluster_proj(
    const int* __restrict__ flag,
    const void* proj_w, const void* proj_b,
    const float* __restrict__ aggf, void* out0)
{
  __shared__ SProj sp;
  if (*flag) proj_body<true>(sp, proj_w, proj_b, aggf, out0);
  else       proj_body<false>(sp, proj_w, proj_b, aggf, out0);
}

}  // namespace

extern "C" void kernel_launch(void* const* d_in, const int* in_sizes, int n_in,
                              void* d_out, int out_size, void* d_ws, size_t ws_size,
                              hipStream_t stream) {
  const void* x         = d_in[0];
  const void* f_w       = d_in[1];
  const void* f_b       = d_in[2];
  const void* v_w       = d_in[3];
  const void* v_b       = d_in[4];
  const void* proj_w    = d_in[5];
  const void* proj_b    = d_in[6];
  const void* sim_alpha = d_in[7];
  const void* sim_beta  = d_in[8];
  const void* centers   = d_in[9];

  // ws layout: [0..15] bytes: dtype flag (int). Then floats:
  //   aggsum[6144] vpool[6144] cnt[256] aggf[6144]  -> ~75 KB total
  int*   flag   = (int*)d_ws;
  float* fws    = (float*)((char*)d_ws + 16);
  float* aggsum = fws;
  float* vpool  = fws + 6144;
  float* cnt    = fws + 12288;
  float* aggf   = fws + 12544;

  // zero flag + accumulators (ws is poisoned 0xAA before every call)
  hipMemsetAsync(d_ws, 0, 16 + 12544 * sizeof(float), stream);

  detect_dtype<<<dim3(1), dim3(256), 0, stream>>>((const unsigned short*)f_w, flag);
  cluster_main<<<dim3(16 * kGrps), dim3(256), 0, stream>>>(
      flag, x, f_w, f_b, v_w, v_b, sim_alpha, sim_beta, centers,
      d_out, aggsum, vpool, cnt);
  cluster_finalize<<<dim3(24), dim3(256), 0, stream>>>(aggsum, vpool, cnt, aggf);
  cluster_amap<<<dim3(kGrps), dim3(256), 0, stream>>>(flag, d_out);
  cluster_proj<<<dim3(16 * kGrps), dim3(256), 0, stream>>>(
      flag, proj_w, proj_b, aggf, d_out);
}